// Round 2
// baseline (88.993 us; speedup 1.0000x reference)
//
#include <hip/hip_runtime.h>

#define L2E 1.44269504088896340736f
#define NEGBIG -9.0e15f

typedef float f32x4 __attribute__((ext_vector_type(4)));
typedef __bf16 bf16x8 __attribute__((ext_vector_type(8)));
typedef __bf16 bf16x4 __attribute__((ext_vector_type(4)));

// D(16x16) = A(16x32)*B(32x16)+C, bf16 in, f32 accum — via builtin so the
// compiler inserts the VALU->MFMA hazard nops (inline asm version NaN'd).
// A: lane l holds row (l&15), k = 8*(l>>4)+e. B: col (l&15), k = 8*(l>>4)+e.
// C/D: col (l&15), row = 4*(l>>4)+reg  [verified layout, m89/m91].
__device__ inline void mfma_bf16(bf16x8 a, bf16x8 b, f32x4& c) {
    c = __builtin_amdgcn_mfma_f32_16x16x32_bf16(a, b, c, 0, 0, 0);
}

// ---------------- Kernel 1: Wh = h @ W, e_src = Wh@a1, e_dst = Wh@a2 ----------------
__global__ __launch_bounds__(256, 2)
void k1_wh(const float* __restrict__ h, const float* __restrict__ W,
           const float* __restrict__ a, __bf16* __restrict__ whT,
           float* __restrict__ esrc, float* __restrict__ edst) {
    const int tid  = threadIdx.x;
    const int lane = tid & 63;
    const int w    = tid >> 6;
    const int blk  = blockIdx.x;        // 0..2047
    const int r0   = blk * 8;           // flat row (b*2048+n), 8 rows/block
    const int b    = r0 >> 11;
    const int n0   = r0 & 2047;

    __shared__ float pt_s[8][4][64];
    __shared__ float whs[64][8];

    float wreg[64];
    {
        const float* Wp = W + (size_t)(w * 64) * 64 + lane;
#pragma unroll
        for (int kk = 0; kk < 64; kk++) wreg[kk] = Wp[(size_t)kk * 64];
    }

    const float* hbase = h + (size_t)r0 * 256 + w * 64;
    for (int rr = 0; rr < 8; rr++) {
        const float4* hp = (const float4*)(hbase + rr * 256);
        float acc = 0.f;
#pragma unroll
        for (int q = 0; q < 16; q++) {
            float4 hv = hp[q];
            acc += hv.x * wreg[4 * q + 0];
            acc += hv.y * wreg[4 * q + 1];
            acc += hv.z * wreg[4 * q + 2];
            acc += hv.w * wreg[4 * q + 3];
        }
        pt_s[rr][w][lane] = acc;
    }
    __syncthreads();

    const float a1 = a[lane];
    const float a2 = a[64 + lane];
#pragma unroll
    for (int rq = 0; rq < 2; rq++) {
        const int rr = w * 2 + rq;      // wave w owns rows 2w, 2w+1
        float v = pt_s[rr][0][lane] + pt_s[rr][1][lane] +
                  pt_s[rr][2][lane] + pt_s[rr][3][lane];
        whs[lane][rr] = v;
        float e1 = v * a1, e2 = v * a2;
#pragma unroll
        for (int d = 1; d < 64; d <<= 1) {
            e1 += __shfl_xor(e1, d);
            e2 += __shfl_xor(e2, d);
        }
        if (lane == 0) { esrc[r0 + rr] = e1; edst[r0 + rr] = e2; }
    }
    __syncthreads();

    // pack + transposed store: WhT[(b*64+o)*2048 + n0 .. n0+7] bf16
    if (tid < 128) {
        const int o = tid >> 1, hf = (tid & 1) * 4;
        float4 v = *(const float4*)&whs[o][hf];
        bf16x4 bv = { (__bf16)v.x, (__bf16)v.y, (__bf16)v.z, (__bf16)v.w };
        *(bf16x4*)(whT + (size_t)(b * 64 + o) * 2048 + n0 + hf) = bv;
    }
}

// ---------------- Kernel 2: fused mask + softmax + PV + ELU ----------------
// Block: 256 thr = 4 waves, 32 rows (2 i-groups x 16) x 64 o (2 o-groups x 32).
__global__ __launch_bounds__(256, 2)
void k2_attn(const int* __restrict__ adj, const __bf16* __restrict__ whT,
             const float* __restrict__ esrc, const float* __restrict__ edst,
             float* __restrict__ out) {
    const int tid  = threadIdx.x;
    const int lane = tid & 63;
    const int w    = tid >> 6;
    const int ig   = w & 1;             // i-group (16 rows)
    const int og   = w >> 1;            // o-group (32 cols)
    const int blk  = blockIdx.x;        // 0..511
    const int b    = blk >> 6;
    const int i0   = (blk & 63) * 32;
    const int r    = lane & 15;
    const int hi   = lane >> 4;         // 0..3

    __shared__ float edst_s[2048];
    __shared__ float esrc_s[32];
    __shared__ float s_s[2][16][68];    // pad 68: conflict-free + 16B aligned

    for (int q = 0; q < 8; q++)
        edst_s[q * 256 + tid] = edst[b * 2048 + q * 256 + tid];
    if (tid < 32) esrc_s[tid] = esrc[b * 2048 + i0 + tid];
    __syncthreads();

    const int srow = tid >> 3;          // 0..31 staging row
    const int scol = (tid & 7) * 8;     // 0..56 staging col base
    const float es_th = esrc_s[srow];
    const int* adjrow = adj + (size_t)(b * 2048 + i0 + srow) * 2048 + scol;
    const __bf16* whTb = whT + (size_t)b * 64 * 2048;

    float m = NEGBIG, lsum = 0.f;
    f32x4 acc0 = {0.f, 0.f, 0.f, 0.f};
    f32x4 acc1 = {0.f, 0.f, 0.f, 0.f};

    int4 pf0 = *(const int4*)(adjrow);
    int4 pf1 = *(const int4*)(adjrow + 4);

    for (int t = 0; t < 32; t++) {
        const int jt = t * 64;
        // ---- stage scores for this 32x64 tile ----
        {
            float4 ed0 = *(const float4*)&edst_s[jt + scol];
            float4 ed1 = *(const float4*)&edst_s[jt + scol + 4];
            int   av[8] = {pf0.x, pf0.y, pf0.z, pf0.w, pf1.x, pf1.y, pf1.z, pf1.w};
            float ev[8] = {ed0.x, ed0.y, ed0.z, ed0.w, ed1.x, ed1.y, ed1.z, ed1.w};
            float sc[8];
#pragma unroll
            for (int e = 0; e < 8; e++) {
                float v = es_th + ev[e];
                v = v > 0.f ? v : 0.2f * v;         // LeakyReLU(0.2)
                sc[e] = av[e] > 0 ? v : NEGBIG;     // adj mask
            }
            if (t < 31) {                           // prefetch next adj tile
                pf0 = *(const int4*)(adjrow + jt + 64);
                pf1 = *(const int4*)(adjrow + jt + 68);
            }
            *(float4*)&s_s[srow >> 4][srow & 15][scol] =
                make_float4(sc[0], sc[1], sc[2], sc[3]);
            *(float4*)&s_s[srow >> 4][srow & 15][scol + 4] =
                make_float4(sc[4], sc[5], sc[6], sc[7]);
        }
        __syncthreads();

        // ---- B fragments (WhT, bf16, L2-resident), issue early ----
        const __bf16* wp = whTb + (size_t)(og * 32 + r) * 2048 + jt + hi * 8;
        bf16x8 bf00 = *(const bf16x8*)(wp);                 // kh0, ot0
        bf16x8 bf10 = *(const bf16x8*)(wp + 32);            // kh1, ot0
        bf16x8 bf01 = *(const bf16x8*)(wp + 16 * 2048);     // kh0, ot1
        bf16x8 bf11 = *(const bf16x8*)(wp + 16 * 2048 + 32);// kh1, ot1

        // ---- online softmax for my 16 rows (row q lives at lanes {q,q+16,q+32,q+48}) ----
        float sv[16];
        *(f32x4*)&sv[0]  = *(const f32x4*)&s_s[ig][r][hi * 8];
        *(f32x4*)&sv[4]  = *(const f32x4*)&s_s[ig][r][hi * 8 + 4];
        *(f32x4*)&sv[8]  = *(const f32x4*)&s_s[ig][r][32 + hi * 8];
        *(f32x4*)&sv[12] = *(const f32x4*)&s_s[ig][r][32 + hi * 8 + 4];

        float mt = sv[0];
#pragma unroll
        for (int e = 1; e < 16; e++) mt = fmaxf(mt, sv[e]);
        mt = fmaxf(mt, __shfl_xor(mt, 16));
        mt = fmaxf(mt, __shfl_xor(mt, 32));
        const float mn    = fmaxf(m, mt);
        const float scale = exp2f((m - mn) * L2E);
        m = mn;

        float p[16];
        float ps = 0.f;
#pragma unroll
        for (int e = 0; e < 16; e++) {
            p[e] = exp2f((sv[e] - mn) * L2E);
            ps += p[e];
        }
        ps += __shfl_xor(ps, 16);
        ps += __shfl_xor(ps, 32);
        lsum = lsum * scale + ps;

        // rescale acc (acc row = 4*hi+reg; scale for row q lives at lane q)
        const float s0 = __shfl(scale, hi * 4 + 0);
        const float s1 = __shfl(scale, hi * 4 + 1);
        const float s2 = __shfl(scale, hi * 4 + 2);
        const float s3 = __shfl(scale, hi * 4 + 3);
        acc0[0] *= s0; acc0[1] *= s1; acc0[2] *= s2; acc0[3] *= s3;
        acc1[0] *= s0; acc1[1] *= s1; acc1[2] *= s2; acc1[3] *= s3;

        bf16x8 pa0, pa1;
#pragma unroll
        for (int e = 0; e < 8; e++) {
            pa0[e] = (__bf16)p[e];
            pa1[e] = (__bf16)p[e + 8];
        }
        mfma_bf16(pa0, bf00, acc0);
        mfma_bf16(pa0, bf01, acc1);
        mfma_bf16(pa1, bf10, acc0);
        mfma_bf16(pa1, bf11, acc1);
        __syncthreads();    // s_s consumed; safe to overwrite next iter
    }

    // ---- epilogue: divide by l, ELU, store ----
#pragma unroll
    for (int reg = 0; reg < 4; reg++) {
        const float lr  = __shfl(lsum, hi * 4 + reg);
        const int   row = i0 + ig * 16 + hi * 4 + reg;
        float v0 = acc0[reg] / lr;
        v0 = v0 > 0.f ? v0 : expm1f(v0);
        float v1 = acc1[reg] / lr;
        v1 = v1 > 0.f ? v1 : expm1f(v1);
        float* op = out + (size_t)(b * 2048 + row) * 64 + og * 32 + r;
        op[0]  = v0;
        op[16] = v1;
    }
}

extern "C" void kernel_launch(void* const* d_in, const int* in_sizes, int n_in,
                              void* d_out, int out_size, void* d_ws, size_t ws_size,
                              hipStream_t stream) {
    const float* h   = (const float*)d_in[0];
    const int*   adj = (const int*)d_in[1];
    const float* W   = (const float*)d_in[2];
    const float* a   = (const float*)d_in[3];
    float* out = (float*)d_out;

    __bf16* whT  = (__bf16*)d_ws;                                  // 8*64*2048 bf16 = 2 MB
    float*  esrc = (float*)((char*)d_ws + (size_t)8 * 64 * 2048 * 2);
    float*  edst = esrc + 8 * 2048;

    hipLaunchKernelGGL(k1_wh, dim3(2048), dim3(256), 0, stream,
                       h, W, a, whT, esrc, edst);
    hipLaunchKernelGGL(k2_attn, dim3(512), dim3(256), 0, stream,
                       adj, whT, esrc, edst, out);
}